// Round 13
// baseline (243.588 us; speedup 1.0000x reference)
//
#include <hip/hip_runtime.h>
#include <hip/hip_bf16.h>

// AttentivePredictionFusion: B=8, T=2048, D=512, H=128. fp32 in, fp32 out.
// R21 (base R20 = 242.6us best):
//  - gemm_body: 3-deep LDS pipeline. R20's 2-deep issued dma(t+1) AFTER
//    barrier(t) -> only the ~200cyc MFMA window to cover ~300-500cyc L2
//    latency -> every K-step exposed the remainder at the next barrier
//    (hit all bf16-DMA operands in mid+fusion). Now dma(t+2) is issued 2
//    steps ahead; barrier waits vmcnt(NBF+NFP) = keep {dma(t+1), regload
//    (t+1)}, drain dma(t). Full drain only at the last step. LDS 48KB,
//    still 3 blocks/CU.
//  - fusion_gemm: launch_bounds(256,3) + XCD-colocation (4 bx-blocks that
//    share an attb row-panel land on one XCD; 3/4 panel reads become L2
//    hits, ~48MB less HBM).
//  - attn_fused: s_setprio(1) around QK and PV MFMA clusters (T5) —
//    cross-block wave arbitration at 2 blocks/CU. Body otherwise R16/R20.

#define APF_B 8
#define APF_T 2048
#define APF_D 512
#define APF_H 128
#define APF_M (APF_B * APF_T)   // 16384

// gemm LDS slot swizzle (u16 units within a 32-u16 row)
#define GSWZ(row) ((((row) >> 1) & 3) << 3)

typedef unsigned short u16;
typedef __attribute__((ext_vector_type(8))) short short8;
typedef __attribute__((ext_vector_type(4))) float f32x4;
typedef __attribute__((ext_vector_type(16))) float f32x16;

static __device__ __forceinline__ u16 f2bf(float x) {
    union { float f; unsigned int u; } cv;
    cv.f = x;
    unsigned int u = cv.u + 0x7FFFu + ((cv.u >> 16) & 1u);  // RNE
    return (u16)(u >> 16);
}
static __device__ __forceinline__ u16 f2bf_hw(float x) {
    union { __hip_bfloat16 h; u16 u; } cv;
    cv.h = __float2bfloat16(x);
    return cv.u;
}

// async global->LDS, 16 B per lane; LDS dest = wave-uniform base + lane*16
static __device__ __forceinline__ void load16_lds(const u16* g, u16* l) {
    __builtin_amdgcn_global_load_lds(
        (const __attribute__((address_space(1))) unsigned int*)g,
        (__attribute__((address_space(3))) unsigned int*)l,
        16, 0, 0);
}

// barrier that keeps the N newest VMEM ops in flight (T4 counted vmcnt)
template <int N>
static __device__ __forceinline__ void bar_keep() {
    if constexpr (N == 0)
        asm volatile("s_waitcnt vmcnt(0) lgkmcnt(0)\ns_barrier" ::: "memory");
    else if constexpr (N == 2)
        asm volatile("s_waitcnt vmcnt(2) lgkmcnt(0)\ns_barrier" ::: "memory");
    else if constexpr (N == 4)
        asm volatile("s_waitcnt vmcnt(4) lgkmcnt(0)\ns_barrier" ::: "memory");
    else if constexpr (N == 6)
        asm volatile("s_waitcnt vmcnt(6) lgkmcnt(0)\ns_barrier" ::: "memory");
    else if constexpr (N == 8)
        asm volatile("s_waitcnt vmcnt(8) lgkmcnt(0)\ns_barrier" ::: "memory");
}

static __device__ __forceinline__ f32x16 zero16() {
    f32x16 v;
#pragma unroll
    for (int i = 0; i < 16; ++i) v[i] = 0.f;
    return v;
}

// ---------------- prep kernel: LDS-tiled weight transposes ----------------
__global__ __launch_bounds__(256) void prep_w(
    const float* __restrict__ Wq, u16* __restrict__ WqT,
    const float* __restrict__ Wk, u16* __restrict__ WkT,
    const float* __restrict__ Wv, u16* __restrict__ WvT,
    const float* __restrict__ Wf, u16* __restrict__ WfT)
{
    __shared__ float tile[64][65];
    int b = blockIdx.x;
    const float* src; u16* dst; int K, N;
    if (b < 16)      { src = Wq; dst = WqT; K = 512;  N = 128; }
    else if (b < 32) { b -= 16; src = Wk; dst = WkT; K = 512;  N = 128; }
    else if (b < 96) { b -= 32; src = Wv; dst = WvT; K = 512;  N = 512; }
    else             { b -= 96; src = Wf; dst = WfT; K = 1024; N = 512; }
    const int ntN = N >> 6;
    const int k0 = (b / ntN) * 64, n0 = (b % ntN) * 64;

    const int tid = threadIdx.x;
#pragma unroll
    for (int rep = 0; rep < 4; ++rep) {
        const int r = (tid >> 4) + rep * 16;     // 0..63 (k)
        const int c = (tid & 15) * 4;            // 0..60 (n)
        const float4 v = *(const float4*)&src[(long)(k0 + r) * N + n0 + c];
        tile[r][c] = v.x; tile[r][c + 1] = v.y;
        tile[r][c + 2] = v.z; tile[r][c + 3] = v.w;
    }
    __syncthreads();
#pragma unroll
    for (int rep = 0; rep < 2; ++rep) {
        const int rn = (tid >> 3) + rep * 32;    // 0..63 (n)
        const int ck = (tid & 7) * 8;            // 0..56 (k)
        short8 o;
#pragma unroll
        for (int j = 0; j < 8; ++j)
            o[j] = (short)f2bf_hw(tile[ck + j][rn]);
        *(short8*)&dst[(long)(n0 + rn) * K + k0 + ck] = o;
    }
}

// ---------------- GEMM body (device function, 3-deep pipeline) -----------
// C[128][128] tile = A[M][K] @ B[N][K]^T (+ bias / + Cadd).
// ADT: 0 = A bf16 (DMA, swizzled src), 1 = A fp32 (reg-stage + HW cvt).
// EPI: 0 bf16 store +bias; 3 fp32 raw +bias; 4 fp32 sigmoid(acc + Cadd).
// BIASM: 0 bias[n]; 1 bias[m].   VBLK: 1 -> blocked [m/32][n/8][m&31][n&7].
// Per step t: regload(t+1) -> bar_keep<NBF+NFP> (drains dma(t); keeps
// dma(t+1)+regload(t+1)) -> issue dma(t+2) -> MFMA(buf t%3) -> write(t+1).
// dma(t+2) gets 2 full steps to land (2-deep exposed ~150cyc/step at L2
// latency). Last step: full drain (no newer ops to count against).
template <int ADT, int BDT, int EPI, int BIASM, int VBLK>
static __device__ __forceinline__ void gemm_body(
    u16 (&smA)[3][4096], u16 (&smB)[3][4096],
    const void* Ap, long lda,
    const void* Bp, long ldb,
    const float* bias, void* Cp, long ldc, int K,
    long row0, long col0, const float* Cadd)
{
    const int tid  = threadIdx.x;
    const int lane = tid & 63;
    const int wid  = tid >> 6;
    const int wr   = wid >> 1;
    const int wc   = wid & 1;

    f32x4 acc[4][4];
#pragma unroll
    for (int i = 0; i < 4; ++i)
#pragma unroll
        for (int j = 0; j < 4; ++j)
            acc[i][j] = (f32x4){0.f, 0.f, 0.f, 0.f};

    const int lrow = (lane >> 4) * 4;
    const int lcol = lane & 15;
    const int q8   = (lane >> 4) * 8;

    float4 ra[2][2], rb[2][2];

    auto loadA = [&](int kb) {
        if (ADT == 1) {
            const float* Af = (const float*)Ap;
#pragma unroll
            for (int rep = 0; rep < 2; ++rep) {
                const int c = tid + rep * 256;
                const int rr = c >> 2, kc = (c & 3) * 8;
                const float* ga = Af + (row0 + rr) * lda + kb + kc;
                ra[rep][0] = *(const float4*)ga;
                ra[rep][1] = *(const float4*)(ga + 4);
            }
        }
    };
    auto loadB = [&](int kb) {
        if (BDT == 1) {
            const float* Bf = (const float*)Bp;
#pragma unroll
            for (int rep = 0; rep < 2; ++rep) {
                const int c = tid + rep * 256;
                const int rr = c >> 2, kc = (c & 3) * 8;
                const float* gb = Bf + (col0 + rr) * ldb + kb + kc;
                rb[rep][0] = *(const float4*)gb;
                rb[rep][1] = *(const float4*)(gb + 4);
            }
        }
    };
    auto dmaA = [&](int buf, int kb) {
        if (ADT == 0) {
            const u16* Ab = (const u16*)Ap;
#pragma unroll
            for (int rep = 0; rep < 2; ++rep) {
                const int c = tid + rep * 256;
                const int rr = c >> 2, kc = (c & 3) * 8;
                const int wbase = (wid * 64 + rep * 256) * 8;
                load16_lds(Ab + (row0 + rr) * lda + kb + (kc ^ GSWZ(rr)),
                           &smA[buf][wbase]);
            }
        }
    };
    auto dmaB = [&](int buf, int kb) {
        if (BDT == 0) {
            const u16* Bb = (const u16*)Bp;
#pragma unroll
            for (int rep = 0; rep < 2; ++rep) {
                const int c = tid + rep * 256;
                const int rr = c >> 2, kc = (c & 3) * 8;
                const int wbase = (wid * 64 + rep * 256) * 8;
                load16_lds(Bb + (col0 + rr) * ldb + kb + (kc ^ GSWZ(rr)),
                           &smB[buf][wbase]);
            }
        }
    };
    auto cvt8 = [&](const float4& a, const float4& b) {
        short8 v;
        v[0] = (short)f2bf_hw(a.x); v[1] = (short)f2bf_hw(a.y);
        v[2] = (short)f2bf_hw(a.z); v[3] = (short)f2bf_hw(a.w);
        v[4] = (short)f2bf_hw(b.x); v[5] = (short)f2bf_hw(b.y);
        v[6] = (short)f2bf_hw(b.z); v[7] = (short)f2bf_hw(b.w);
        return v;
    };
    auto writeA = [&](int buf) {
        if (ADT == 1) {
#pragma unroll
            for (int rep = 0; rep < 2; ++rep) {
                const int c = tid + rep * 256;
                *(short8*)&smA[buf][(c * 8) ^ GSWZ(c >> 2)] =
                    cvt8(ra[rep][0], ra[rep][1]);
            }
        }
    };
    auto writeB = [&](int buf) {
        if (BDT == 1) {
#pragma unroll
            for (int rep = 0; rep < 2; ++rep) {
                const int c = tid + rep * 256;
                *(short8*)&smB[buf][(c * 8) ^ GSWZ(c >> 2)] =
                    cvt8(rb[rep][0], rb[rep][1]);
            }
        }
    };

    // per-thread VMEM instrs per step: bf16 DMA operand = 2, fp32 reg = 4
    constexpr int NBF = (ADT == 0 ? 2 : 0) + (BDT == 0 ? 2 : 0);
    constexpr int NFP = (ADT == 1 ? 4 : 0) + (BDT == 1 ? 4 : 0);

    const int NT = K / 32;
    // prologue: tile 0 staged (both paths), tile 1 DMA issued (bf16 path)
    loadA(0); loadB(0);
    writeA(0); writeB(0);
    dmaA(0, 0); dmaB(0, 0);
    if (NT > 1) { dmaA(1, 32); dmaB(1, 32); }

    for (int t = 0; t < NT; ++t) {
        const int c3 = t % 3;
        if (t + 1 < NT) { loadA((t + 1) * 32); loadB((t + 1) * 32); }
        // drain dma(t); keep dma(t+1) + regload(t+1) in flight
        if (t + 1 < NT) bar_keep<NBF + NFP>();
        else            bar_keep<0>();
        if (t + 2 < NT) { dmaA((t + 2) % 3, (t + 2) * 32);
                          dmaB((t + 2) % 3, (t + 2) * 32); }

        short8 av[4], bv4[4];
#pragma unroll
        for (int ti = 0; ti < 4; ++ti) {
            const int arow = wr * 64 + ti * 16 + lcol;
            av[ti] = *(const short8*)&smA[c3][arow * 32 + (q8 ^ GSWZ(arow))];
        }
#pragma unroll
        for (int tj = 0; tj < 4; ++tj) {
            const int brow = wc * 64 + tj * 16 + lcol;
            bv4[tj] = *(const short8*)&smB[c3][brow * 32 + (q8 ^ GSWZ(brow))];
        }

#pragma unroll
        for (int ti = 0; ti < 4; ++ti)
#pragma unroll
            for (int tj = 0; tj < 4; ++tj)
                acc[ti][tj] = __builtin_amdgcn_mfma_f32_16x16x32_bf16(
                    av[ti], bv4[tj], acc[ti][tj], 0, 0, 0);

        if (t + 1 < NT) { writeA((t + 1) % 3); writeB((t + 1) % 3); }
    }

#pragma unroll
    for (int ti = 0; ti < 4; ++ti) {
        const long m0t = row0 + wr * 64 + ti * 16 + lrow;
#pragma unroll
        for (int tj = 0; tj < 4; ++tj) {
            const long n = col0 + wc * 64 + tj * 16 + lcol;
            const float bn = (BIASM == 0 && bias != nullptr) ? bias[n] : 0.f;
            if (EPI == 0) {
                u16* C = (u16*)Cp;
#pragma unroll
                for (int r = 0; r < 4; ++r) {
                    const long m = m0t + r;
                    const float bm = (BIASM == 1) ? bias[m] : bn;
                    long idx;
                    if (VBLK) {
                        idx = ((((m >> 5) * 256) + (n >> 3)) << 8) +
                              ((m & 31) << 3) + (n & 7);
                    } else {
                        idx = m * ldc + n;
                    }
                    C[idx] = f2bf_hw(acc[ti][tj][r] + bm);
                }
            } else if (EPI == 3) {
                float* C = (float*)Cp;
#pragma unroll
                for (int r = 0; r < 4; ++r)
                    C[(m0t + r) * ldc + n] = acc[ti][tj][r] + bn;
            } else {  // EPI == 4
                float* C = (float*)Cp;
#pragma unroll
                for (int r = 0; r < 4; ++r) {
                    const float val = acc[ti][tj][r] + Cadd[(m0t + r) * ldc + n];
                    C[(m0t + r) * ldc + n] = 1.0f / (1.0f + expf(-val));
                }
            }
        }
    }
}

// ---------------- mid GEMMs: q/k proj + vT + Cpre, one 1280-block launch ---
// bid<256: qk. zz=bid>>7 (0:q pred/WqT, 1:k x/WkT), by=bid&127 (no reuse).
// 256..767: vT. XCD-swizzle: zz = t&7 (all 64 blocks of batch z colocate on
//   XCD z; x[z] 4MB fp32 = one L2). idx=t>>3: bx=idx&15, by=idx>>4.
// 768..1279: Cpre. XCD-swizzle: xcd=t&7, j=t>>3, by = xcd + 8*(j>>2),
//   bx = j&3 -> pred panels colocate; 3/4 reads hit L2.
__global__ __launch_bounds__(256, 3) void mid_gemms(
    const float* __restrict__ x, const float* __restrict__ pred,
    const u16* __restrict__ WqT, const u16* __restrict__ WkT,
    const u16* __restrict__ WvT, const u16* __restrict__ WfT,
    const float* __restrict__ bq, const float* __restrict__ bk,
    const float* __restrict__ bv, const float* __restrict__ bfu,
    u16* __restrict__ qb, u16* __restrict__ kbuf, u16* __restrict__ vTb,
    float* __restrict__ Cpre)
{
    __shared__ u16 smA[3][4096];
    __shared__ u16 smB[3][4096];

    const int bid = blockIdx.x;
    if (bid < 256) {
        const int zz = bid >> 7, by = bid & 127;
        gemm_body<1, 0, 0, 0, 0>(smA, smB,
            zz ? (const void*)x : (const void*)pred, APF_D,
            zz ? WkT : WqT, APF_D,
            zz ? bk : bq, zz ? (void*)kbuf : (void*)qb, APF_H, APF_D,
            (long)by * 128, 0, nullptr);
    } else if (bid < 768) {
        const int t = bid - 256;          // t%8 == XCD (256%8==0)
        const int zz = t & 7;             // batch z pinned to XCD z
        const int idx = t >> 3;           // 0..63
        const int bx = idx & 15, by = idx >> 4;
        gemm_body<0, 1, 0, 1, 1>(smA, smB,
            WvT, APF_D,
            (const void*)(x + (long)zz * APF_T * APF_D), APF_D,
            bv, (void*)(vTb + (long)zz * 1048576L), APF_T, APF_D,
            (long)by * 128, (long)bx * 128, nullptr);
    } else {
        const int t = bid - 768;          // t%8 == XCD (768%8==0)
        const int xcd = t & 7, j = t >> 3;        // j 0..63
        const int by = xcd + 8 * (j >> 2);        // pred panels colocate
        const int bx = j & 3;
        gemm_body<1, 0, 3, 0, 0>(smA, smB,
            (const void*)pred, APF_D,
            WfT, 1024,
            bfu, (void*)Cpre, APF_D, APF_D,
            (long)by * 128, (long)bx * 128, nullptr);
    }
}

// ---------------- fusion GEMM: out = sigmoid(att@Wf_bot + Cpre) ----------
// 1D grid 512, XCD-colocated: the 4 bx-blocks sharing an attb row-panel get
// the same XCD (by = xcd + 8*(j>>2), bx = j&3) -> 3/4 panel reads hit L2.
__global__ __launch_bounds__(256, 3) void fusion_gemm(
    const u16* __restrict__ attb, const u16* __restrict__ WfT,
    const float* __restrict__ Cpre, float* __restrict__ out)
{
    __shared__ u16 smA[3][4096];
    __shared__ u16 smB[3][4096];
    const int t = blockIdx.x;                 // 512 blocks, 512%8==0
    const int xcd = t & 7, j = t >> 3;        // j 0..63
    const int by = xcd + 8 * (j >> 2);        // attb panels colocate
    const int bx = j & 3;
    gemm_body<0, 0, 4, 0, 0>(smA, smB,
        (const void*)attb, APF_D,
        WfT + 512, 1024,
        nullptr, (void*)out, APF_D, APF_D,
        (long)by * 128, (long)bx * 128, Cpre);
}

// ---------------- fused attention (R16/R20 body + T5 setprio) ------------
// Grid 512 blocks. bid&7 = batch z (XCD L2); (bid>>3)&31 = Q-tile (64 rows);
// bid>>8 = d-chunk (256 cols). 4 waves (qb=w>>1, sb=w&1), s-block 64, 32 it.
// Per iter (ONE __syncthreads — drains each wave's vmcnt+lgkmcnt, so after
// it ALL waves' DMA landed; race-free):
//   A: QK on sK[cur] (8 MFMA, Q from regs); issue K(kt+1) DMA -> sK[cur^1];
//      V(kt) global->reg (8 frags, blocked layout).
//   B: exp + rowsum + sP[cur].  [__syncthreads]
//   C: PV on sP[cur] (16 MFMA).
// setprio(1) wraps both MFMA clusters (T5): at 2 independent blocks/CU the
// scheduler can favor the MFMA-issuing wave over the other block's staging.
// LDS 49.8KB -> 2 blocks/CU. launch_bounds(256,2): no spill.
__global__ __launch_bounds__(256, 2) void attn_fused(
    const u16* __restrict__ qg, const u16* __restrict__ kg,
    const u16* __restrict__ vTg, u16* __restrict__ attg)
{
    __shared__ u16 sK[2][64 * 128];  // 2 x 16 KB
    __shared__ u16 sP[2][64 * 64];   // 2 x 8 KB
    __shared__ float sRS[192];       // partials [4w][32] + inv [64]

    const int tid  = threadIdx.x;
    const int lane = tid & 63;
    const int w    = tid >> 6;       // 0..3
    const int l31  = lane & 31;
    const int hi   = lane >> 5;      // 0..1
    const int qb   = w >> 1;         // QK q-block
    const int sb   = w & 1;          // QK s-block

    const int  bid = blockIdx.x;
    const long z   = bid & 7;
    const int  r   = bid >> 3;
    const long q0  = (long)(r & 31) * 64;
    const long d0  = (long)(r >> 5) * 256;

    const u16* kbase0 = kg + z * (long)APF_T * APF_H;

    // prologue: K tile 0 DMA (pre-swizzled source, linear LDS)
#pragma unroll
    for (int rep = 0; rep < 4; ++rep) {
        const int c    = tid + rep * 256;     // 0..1023
        const int row  = c >> 4;
        const int col8 = (c & 15) * 8;
        load16_lds(kbase0 + row * APF_H + (col8 ^ ((row & 15) << 3)),
                   &sK[0][c * 8]);
    }

    // Q hoist: loop-invariant fragments (lane's q-row = q0 + qb*32 + l31)
    short8 qf[8];
    {
        const u16* qsrc = qg + (z * APF_T + q0 + qb * 32 + l31) * APF_H;
#pragma unroll
        for (int ks = 0; ks < 8; ++ks)
            qf[ks] = *(const short8*)(qsrc + ks * 16 + hi * 8);
    }
    __syncthreads();   // full drain once: sK[0] + qf ready

    f32x16 oacc[2][2];
#pragma unroll
    for (int i = 0; i < 2; ++i)
#pragma unroll
        for (int j = 0; j < 2; ++j) oacc[i][j] = zero16();
    f32x16 rsacc = zero16();

    // blocked vT base for this wave: [z][dblk][s8][d&31][s&7]
    const long dblk0 = (d0 >> 5) + w * 2;
    const u16* vzb = vTg + z * 1048576L + dblk0 * 65536L + (long)l31 * 8;

    const int krow = sb * 32 + l31;
    const int pcol = sb * 32 + l31;

    int cur = 0;
    for (int kt = 0; kt < APF_T / 64; ++kt) {
        // phase A: QK^T on sK[cur] (Q from regs)
        f32x16 sacc = zero16();
        __builtin_amdgcn_s_setprio(1);
#pragma unroll
        for (int ks = 0; ks < 8; ++ks) {
            const int colk = ks * 16 + hi * 8;
            const short8 bv =
                *(const short8*)&sK[cur][krow * 128 + (colk ^ ((krow & 15) << 3))];
            sacc = __builtin_amdgcn_mfma_f32_32x32x16_bf16(qf[ks], bv, sacc, 0, 0, 0);
        }
        __builtin_amdgcn_s_setprio(0);

        // issue next K tile DMA into the other buffer (drains at the barrier)
        if (kt + 1 < APF_T / 64) {
            const u16* ksrc = kbase0 + (long)(kt + 1) * 64 * APF_H;
#pragma unroll
            for (int rep = 0; rep < 4; ++rep) {
                const int c    = tid + rep * 256;
                const int row  = c >> 4;
                const int col8 = (c & 15) * 8;
                load16_lds(ksrc + row * APF_H + (col8 ^ ((row & 15) << 3)),
                           &sK[cur ^ 1][c * 8]);
            }
        }

        // V prefetch (blocked layout: contiguous 1KB per instr), 8 frags
        const long sbase = (long)kt * 8 + hi;
        short8 vf[2][4];
#pragma unroll
        for (int dt = 0; dt < 2; ++dt)
#pragma unroll
            for (int ks = 0; ks < 4; ++ks)
                vf[dt][ks] = *(const short8*)(vzb + dt * 65536L + (sbase + ks * 2) * 256);

        // phase B: exp + rowsum + P -> sP[cur] (swizzled)
#pragma unroll
        for (int rg = 0; rg < 16; ++rg) {
            const float e = __expf(sacc[rg]);
            rsacc[rg] += e;
            const int prow = qb * 32 + (rg & 3) + 8 * (rg >> 2) + 4 * hi;
            sP[cur][prow * 64 + (pcol ^ ((prow & 7) << 3))] = f2bf(e);
        }
        __syncthreads();   // sP[cur] visible; all waves' K-DMA + V landed

        // phase C: PV on sP[cur]: O[64][w*64..+64] += P @ V^T
        __builtin_amdgcn_s_setprio(1);
#pragma unroll
        for (int ks = 0; ks < 4; ++ks) {
            const int colk = ks * 16 + hi * 8;
            short8 pa[2];
#pragma unroll
            for (int qt = 0; qt < 2; ++qt) {
                const int prow = qt * 32 + l31;
                pa[qt] = *(const short8*)&sP[cur][prow * 64 + (colk ^ ((prow & 7) << 3))];
            }
#pragma unroll
            for (int dt = 0; dt < 2; ++dt)
#pragma unroll
                for (int qt = 0; qt < 2; ++qt)
                    oacc[qt][dt] = __builtin_amdgcn_mfma_f32_32x32x16_bf16(
                        pa[qt], vf[dt][ks], oacc[qt][dt], 0, 0, 0);
        }
        __builtin_amdgcn_s_setprio(0);
        cur ^= 1;
    }

    // rowsum: reduce over the 32 s-cols (l31), publish per-wave partials
#pragma unroll
    for (int rg = 0; rg < 16; ++rg) {
        float s = rsacc[rg];
        s += __shfl_xor(s, 1);
        s += __shfl_xor(s, 2);
        s += __shfl_xor(s, 4);
        s += __shfl_xor(s, 8);
        s += __shfl_xor(s, 16);
        rsacc[rg] = s;
    }
    if (l31 == 0) {
#pragma unroll
        for (int rg = 0; rg < 16; ++rg) {
            const int row = (rg & 3) + 8 * (rg >> 2) + 4 * hi;   // 0..31
            sRS[w * 32 + row] = rsacc[rg];
        }
    }
    __syncthreads();
    if (tid < 64) {
        const int qb2 = tid >> 5, r2 = tid & 31;
        sRS[128 + tid] = 1.0f / (sRS[(qb2 * 2 + 0) * 32 + r2] +
                                 sRS[(qb2 * 2 + 1) * 32 + r2]);
    }
    __syncthreads();

    // store: 64 q rows x own 64 d cols
    const long rowg0 = z * APF_T + q0;
    const long colg0 = d0 + (long)w * 64;
#pragma unroll
    for (int qt = 0; qt < 2; ++qt)
#pragma unroll
        for (int rg = 0; rg < 16; ++rg) {
            const int row = qt * 32 + (rg & 3) + 8 * (rg >> 2) + 4 * hi;
            const float inv = sRS[128 + row];
#pragma unroll
            for (int dt = 0; dt < 2; ++dt)
                attg[(rowg0 + row) * APF_D + colg0 + dt * 32 + l31] =
                    f2bf(oacc[qt][dt][rg] * inv);
        }
}

extern "C" void kernel_launch(void* const* d_in, const int* in_sizes, int n_in,
                              void* d_out, int out_size, void* d_ws, size_t ws_size,
                              hipStream_t stream)
{
    (void)in_sizes; (void)n_in; (void)out_size; (void)ws_size;

    const float* x    = (const float*)d_in[0];
    const float* pred = (const float*)d_in[1];
    const float* Wq   = (const float*)d_in[2];
    const float* bq   = (const float*)d_in[3];
    const float* Wk   = (const float*)d_in[4];
    const float* bk   = (const float*)d_in[5];
    const float* Wv   = (const float*)d_in[6];
    const float* bv   = (const float*)d_in[7];
    const float* Wf   = (const float*)d_in[8];
    const float* bfu  = (const float*)d_in[9];

    // Workspace: Cpre fp32 32MB first, then u16 arrays (~42MB)
    float* Cpre = (float*)d_ws;                        // [16384][512] fp32
    u16* wsp  = (u16*)(Cpre + (long)APF_M * APF_D);
    u16* qb   = wsp;                                   // [16384][128]
    u16* kbuf = qb   + (long)APF_M * APF_H;            // [16384][128]
    u16* vTb  = kbuf + (long)APF_M * APF_H;            // [8][16][256][32][8] blocked
    u16* attb = vTb  + (long)APF_M * APF_D;            // [16384][512]
    u16* WqT  = attb + (long)APF_M * APF_D;            // [128][512]
    u16* WkT  = WqT  + (long)APF_H * APF_D;            // [128][512]
    u16* WvT  = WkT  + (long)APF_H * APF_D;            // [512][512]
    u16* WfT  = WvT  + (long)APF_D * APF_D;            // [512][1024]

    const dim3 thr(256);

    // weights -> bf16 transposed (LDS-tiled, coalesced)
    prep_w<<<dim3(224), thr, 0, stream>>>(Wq, WqT, Wk, WkT, Wv, WvT, Wf, WfT);

    // q,k projections + vT + Cpre(pred@Wf_top+bf) in one 1280-block launch
    mid_gemms<<<dim3(1280), thr, 0, stream>>>(
        x, pred, WqT, WkT, WvT, WfT, bq, bk, bv, bfu, qb, kbuf, vTb, Cpre);

    // fused attention: att = softmax(q k^T) v
    attn_fused<<<dim3(512), thr, 0, stream>>>(qb, kbuf, vTb, attb);

    // out = sigmoid(att @ Wf_bot + Cpre)
    fusion_gemm<<<dim3(512), thr, 0, stream>>>(attb, WfT, Cpre,
                                               (float*)d_out);
}